// Round 10
// baseline (77.199 us; speedup 1.0000x reference)
//
#include <hip/hip_runtime.h>
#include <math.h>

constexpr int BGR=1024, NN=128, EG=2048, FIN=30, H1=30, H2=50, K1=103, K2=83, FCW=100;
constexpr int NT=512;
constexpr int EPT=EG/NT;          // 4 packed edges/thread
constexpr int EGP=EG+NN*4;        // padded CSR capacity
constexpr int XBSZ=(NN+1)*32;     // 129 rows x 32 floats; row 128 = zero row (pad sentinel)

// row r, feature i -> dword r*32 + (((i>>2)+r)&7)*4 + (i&3)

__device__ __forceinline__ void row_add(const float* XB, int s, int cq, float4&a0, float4&a1){
  int b=s<<5, r=s&7;
  float4 v0=*(const float4*)&XB[b+(((cq  +r)&7)<<2)];
  float4 v1=*(const float4*)&XB[b+(((cq+1+r)&7)<<2)];
  a0.x+=v0.x; a0.y+=v0.y; a0.z+=v0.z; a0.w+=v0.w;
  a1.x+=v1.x; a1.y+=v1.y; a1.z+=v1.z; a1.w+=v1.w;
}

__global__ __launch_bounds__(NT,8) void gnn_fused(
    const float* __restrict__ x, const int* __restrict__ ei,
    const float* __restrict__ W1, const float* __restrict__ b1, const float* __restrict__ p1,
    const float* __restrict__ W2, const float* __restrict__ b2, const float* __restrict__ p2,
    const float* __restrict__ fc1W, const float* __restrict__ fc1b,
    const float* __restrict__ fc2W, const float* __restrict__ fc2b,
    float* __restrict__ out)
{
  const int g=blockIdx.x, tid=threadIdx.x, lane=tid&63, wv=tid>>6;
  const int qt=wv&3;                      // wave-uniform feature quarter
  const int nG=(tid>>8)*64+lane;          // node: waves 0-3 -> 0..63, 4-7 -> 64..127
  const int qtu=__builtin_amdgcn_readfirstlane(qt);
  const int cq=qtu<<1;                    // first of the quarter's 2 chunks

  __shared__ float XB[XBSZ];
  __shared__ unsigned char eord[EGP];
  __shared__ int cur[NN];
  __shared__ short cstart[NN], deg1s[NN];
  __shared__ float dsc[NN], dv2[NN];
  __shared__ signed char rmap[NN], rm2[NN];
  __shared__ float sd[4*NN];
  __shared__ float pmx[8*13], psm[8*13], pol[2*H2], zfc[FCW];
  __shared__ int sh_wtot;

  // ---- packed edges in registers: src | dst<<8 ----
  int epk[EPT];
  {
    const int* srcg=ei+(size_t)g*EG;
    const int* dstg=ei+(size_t)BGR*EG+(size_t)g*EG;
    #pragma unroll
    for(int j=0;j<EPT;j++){ int e=tid+j*NT; epk[j]=(srcg[e]&127)|((dstg[e]&127)<<8); }
  }
  // ---- stage x (swizzled); zero pads + zero row 128 ----
  for(int l2=tid;l2<NN*15;l2+=NT){
    int n=l2/15, i=(l2-n*15)*2;
    float2 v=*(const float2*)&x[(size_t)g*NN*FIN+n*FIN+i];
    *(float2*)&XB[(n<<5)+((((i>>2)+n)&7)<<2)+(i&3)]=v;
  }
  if(tid<NN){
    int o=(tid<<5)+((((7)+tid)&7)<<2);
    XB[o+2]=0.f; XB[o+3]=0.f;
    cur[tid]=0;
  }
  if(tid>=NN && tid<NN+32) XB[NN*32+(tid-NN)]=0.f;
  __syncthreads();

  // ================= CSR build (layer 1, the only one) =================
  #pragma unroll
  for(int j=0;j<EPT;j++) atomicAdd(&cur[epk[j]>>8],1);
  __syncthreads();
  {
    int mydeg=(tid<NN)?cur[tid]:0;
    int mydeg4=(mydeg+3)&~3;
    int v=mydeg4;
    #pragma unroll
    for(int off=1;off<64;off<<=1){ int t=__shfl_up(v,off,64); if(lane>=off)v+=t; }
    if(tid==63) sh_wtot=v;
    for(int l=tid;l<EGP/4;l+=NT) ((int*)eord)[l]=0x80808080;   // sentinel = zero row 128
    __syncthreads();
    if(tid<NN){
      int start=v-mydeg4+((tid>=64)?sh_wtot:0);
      cur[tid]=start; cstart[tid]=(short)start; deg1s[tid]=(short)mydeg;
      dsc[tid]=1.0f/sqrtf((float)mydeg+1.0f);                   // dinv1
    }
  }
  __syncthreads();
  #pragma unroll
  for(int j=0;j<EPT;j++){ int p=atomicAdd(&cur[epk[j]>>8],1); eord[p]=(unsigned char)(epk[j]&255); }
  __syncthreads();

  // ---- prescale x rows by dinv1 (own 2 chunks) ----
  {
    float di=dsc[nG];
    int b=nG<<5, r=nG&7;
    float4* s0=(float4*)&XB[b+(((cq  +r)&7)<<2)];
    float4* s1=(float4*)&XB[b+(((cq+1+r)&7)<<2)];
    float4 v0=*s0, v1=*s1;
    v0.x*=di; v0.y*=di; v0.z*=di; v0.w*=di;
    v1.x*=di; v1.y*=di; v1.z*=di; v1.w*=di;
    *s0=v0; *s1=v1;
  }
  __syncthreads();

  // ================= gather1: pure row-sum =================
  float4 a0={0,0,0,0}, a1={0,0,0,0};
  {
    int e0=cstart[nG], dg=deg1s[nG];
    int kend=e0+((dg+3)&~3);
    for(int k=e0;k<kend;k+=4){
      uchar4 ss=*(const uchar4*)&eord[k];
      row_add(XB,ss.x,cq,a0,a1);
      row_add(XB,ss.y,cq,a0,a1);
      row_add(XB,ss.z,cq,a0,a1);
      row_add(XB,ss.w,cq,a0,a1);
    }
    float di=dsc[nG];
    float cn=1.0f/(di*((float)dg+1.0f));   // self weight on prescaled row
    int b=nG<<5, r=nG&7;
    float4 v0=*(const float4*)&XB[b+(((cq  +r)&7)<<2)];
    float4 v1=*(const float4*)&XB[b+(((cq+1+r)&7)<<2)];
    a0.x=fmaf(cn,v0.x,a0.x*di); a0.y=fmaf(cn,v0.y,a0.y*di);
    a0.z=fmaf(cn,v0.z,a0.z*di); a0.w=fmaf(cn,v0.w,a0.w*di);
    a1.x=fmaf(cn,v1.x,a1.x*di); a1.y=fmaf(cn,v1.y,a1.y*di);
    a1.z=fmaf(cn,v1.z,a1.z*di); a1.w=fmaf(cn,v1.w,a1.w*di);
  }
  __syncthreads();                  // all x' reads done
  {
    int b=nG<<5, r=nG&7;
    *(float4*)&XB[b+(((cq+r)&7)<<2)]=a0;
    if(qtu<3) *(float4*)&XB[b+(((cq+1+r)&7)<<2)]=a1;
    else      *(float2*)&XB[b+(((cq+1+r)&7)<<2)]=make_float2(a1.x,a1.y);
  }
  __syncthreads();                  // agg1 ready

  // ================= mm1 (scalar W, streamed A) + pool1 partial ==============
  float h[8];
  {
    const int CNT=(qtu<3)?8:6;
    const float* Wq=W1+qtu*8; const float* bq=b1+qtu*8; const float* pq=p1+qtu*8;
    #pragma unroll
    for(int jo=0;jo<8;jo++) h[jo]=(jo<CNT)?bq[jo]:0.f;
    int b=nG<<5, r=nG&7;
    #pragma unroll
    for(int c=0;c<8;c++){
      float4 a=*(const float4*)&XB[b+(((c+r)&7)<<2)];
      #pragma unroll
      for(int e=0;e<4;e++){
        int i=c*4+e;
        if(i<H1){
          float ai=(e==0)?a.x:(e==1)?a.y:(e==2)?a.z:a.w;
          const float* wr=Wq+i*H1;
          #pragma unroll
          for(int jo=0;jo<8;jo++) if(jo<CNT) h[jo]=fmaf(ai,wr[jo],h[jo]);
        }
      }
    }
    float dd=0.f;
    #pragma unroll
    for(int jo=0;jo<8;jo++) if(jo<CNT){ h[jo]=fmaxf(h[jo],0.f); dd+=h[jo]*pq[jo]; }
    sd[qt*NN+nG]=dd;
  }
  __syncthreads();
  if(tid<NN){
    float nr=0.f;
    #pragma unroll
    for(int i=0;i<H1;i++){ float pv=p1[i]; nr+=pv*pv; }
    float dt=sd[tid]+sd[NN+tid]+sd[2*NN+tid]+sd[3*NN+tid];
    dsc[tid]=tanhf(dt/sqrtf(nr));          // score1 (dinv1 no longer needed)
  }
  __syncthreads();
  {  // rank1 (4-way split): kept iff stable-rank < K1
    int nR=tid>>2, sub=tid&3;
    float si=dsc[nR];
    int m0=sub<<5, rr=0;
    for(int m=m0;m<m0+32;m++){ float sm=dsc[m]; rr+=(sm>si)||(sm==si&&m<nR); }
    rr+=__shfl_xor(rr,1,64); rr+=__shfl_xor(rr,2,64);
    if(sub==0) rmap[nR]=(rr<K1)?(signed char)1:(signed char)-1;
  }
  __syncthreads();
  // ---- deg2: masked count on original edges (NO CSR rebuild) ----
  if(tid<NN) cur[tid]=0;
  __syncthreads();
  #pragma unroll
  for(int j=0;j<EPT;j++){
    int s=epk[j]&255, d=epk[j]>>8;
    if(rmap[s]>0 && rmap[d]>0) atomicAdd(&cur[d],1);
  }
  __syncthreads();
  if(tid<NN) dv2[tid]=1.0f/sqrtf((float)cur[tid]+1.0f);
  __syncthreads();

  // ---- h1g' write: gated + dinv2-prescaled (dropped nodes -> zero rows) ----
  {
    bool kept=rmap[nG]>0;
    float gv=kept?dsc[nG]*dv2[nG]:0.f;
    int b=nG<<5, r=nG&7;
    *(float4*)&XB[b+(((cq+r)&7)<<2)]=make_float4(h[0]*gv,h[1]*gv,h[2]*gv,h[3]*gv);
    if(qtu<3) *(float4*)&XB[b+(((cq+1+r)&7)<<2)]=make_float4(h[4]*gv,h[5]*gv,h[6]*gv,h[7]*gv);
    else      *(float2*)&XB[b+(((cq+1+r)&7)<<2)]=make_float2(h[4]*gv,h[5]*gv);
  }
  __syncthreads();

  // ================= gather2: pure row-sum over ORIGINAL CSR =================
  float4 c0={0,0,0,0}, c1={0,0,0,0};
  {
    int e0=cstart[nG], dg=deg1s[nG];
    int kend=e0+((dg+3)&~3);
    for(int k=e0;k<kend;k+=4){
      uchar4 ss=*(const uchar4*)&eord[k];
      row_add(XB,ss.x,cq,c0,c1);
      row_add(XB,ss.y,cq,c0,c1);
      row_add(XB,ss.z,cq,c0,c1);
      row_add(XB,ss.w,cq,c0,c1);
    }
    float d2=dv2[nG];
    bool kept=rmap[nG]>0;
    float selfc=(kept?dsc[nG]:0.f)/((float)cur[nG]+1.0f);  // h1g[n]/(deg2+1), h in regs
    c0.x=fmaf(selfc,h[0],c0.x*d2); c0.y=fmaf(selfc,h[1],c0.y*d2);
    c0.z=fmaf(selfc,h[2],c0.z*d2); c0.w=fmaf(selfc,h[3],c0.w*d2);
    c1.x=fmaf(selfc,h[4],c1.x*d2); c1.y=fmaf(selfc,h[5],c1.y*d2);
    c1.z=fmaf(selfc,h[6],c1.z*d2); c1.w=fmaf(selfc,h[7],c1.w*d2);
  }
  __syncthreads();                  // all h1g' reads done
  {
    int b=nG<<5, r=nG&7;
    *(float4*)&XB[b+(((cq+r)&7)<<2)]=c0;
    if(qtu<3) *(float4*)&XB[b+(((cq+1+r)&7)<<2)]=c1;
    else      *(float2*)&XB[b+(((cq+1+r)&7)<<2)]=make_float2(c1.x,c1.y);
  }
  __syncthreads();                  // agg2 ready

  // ================= mm2 (scalar W) + pool2 partial =================
  float oc[13];
  {
    const int CNT=(qtu<3)?13:11;
    const float* Wq=W2+qtu*13; const float* bq=b2+qtu*13; const float* pq=p2+qtu*13;
    #pragma unroll
    for(int jo=0;jo<13;jo++) oc[jo]=(jo<CNT)?bq[jo]:0.f;
    int b=nG<<5, r=nG&7;
    #pragma unroll
    for(int c=0;c<8;c++){
      float4 a=*(const float4*)&XB[b+(((c+r)&7)<<2)];
      #pragma unroll
      for(int e=0;e<4;e++){
        int i=c*4+e;
        if(i<H1){
          float ai=(e==0)?a.x:(e==1)?a.y:(e==2)?a.z:a.w;
          const float* wr=Wq+i*H2;
          #pragma unroll
          for(int jo=0;jo<13;jo++) if(jo<CNT) oc[jo]=fmaf(ai,wr[jo],oc[jo]);
        }
      }
    }
    float dd=0.f;
    #pragma unroll
    for(int jo=0;jo<13;jo++) if(jo<CNT){ oc[jo]=fmaxf(oc[jo],0.f); dd+=oc[jo]*pq[jo]; }
    sd[qt*NN+nG]=dd;
  }
  __syncthreads();
  if(tid<NN){
    float nr=0.f;
    #pragma unroll
    for(int i=0;i<H2;i++){ float pv=p2[i]; nr+=pv*pv; }
    float dt=sd[tid]+sd[NN+tid]+sd[2*NN+tid]+sd[3*NN+tid];
    dsc[tid]=tanhf(dt/sqrtf(nr));          // score2
  }
  __syncthreads();
  {  // rank2 among kept1 nodes (ties measure-zero on random scores)
    int nR=tid>>2, sub=tid&3;
    bool k1=rmap[nR]>0;
    float si=dsc[nR];
    int m0=sub<<5, rr=0;
    for(int m=m0;m<m0+32;m++){
      if(rmap[m]>0){ float sm=dsc[m]; rr+=(sm>si)||(sm==si&&m<nR); }
    }
    rr+=__shfl_xor(rr,1,64); rr+=__shfl_xor(rr,2,64);
    if(sub==0) rm2[nR]=(k1&&rr<K2)?(signed char)1:(signed char)-1;
  }
  __syncthreads();

  // ================= gated global max/mean =================
  {
    bool kept=rm2[nG]>0;
    float gv=kept?dsc[nG]:0.f;
    float mx[13], sm[13];
    #pragma unroll
    for(int j=0;j<13;j++){ float v=oc[j]*gv; sm[j]=kept?v:0.f; mx[j]=kept?v:-3.4e38f; }
    #pragma unroll
    for(int off=1;off<64;off<<=1){
      #pragma unroll
      for(int j=0;j<13;j++){
        mx[j]=fmaxf(mx[j],__shfl_xor(mx[j],off,64));
        sm[j]+=__shfl_xor(sm[j],off,64);
      }
    }
    if(lane==0){
      #pragma unroll
      for(int j=0;j<13;j++){ pmx[wv*13+j]=mx[j]; psm[wv*13+j]=sm[j]; }
    }
  }
  __syncthreads();
  if(tid<H2){
    int q=tid/13, j=tid-q*13;
    float m=fmaxf(pmx[q*13+j],pmx[(q+4)*13+j]);
    float s=psm[q*13+j]+psm[(q+4)*13+j];
    pol[tid]=m; pol[H2+tid]=s*(1.0f/(float)K2);
  }
  __syncthreads();

  // ================= fc1 + fc2 =================
  if(tid<FCW){
    float acc=fc1b[tid];
    #pragma unroll 4
    for(int i=0;i<2*H2;i++) acc+=pol[i]*fc1W[i*FCW+tid];
    zfc[tid]=fmaxf(acc,0.f);
  }
  __syncthreads();
  if(tid<64){
    float a=0.f;
    for(int j=tid;j<FCW;j+=64) a+=zfc[j]*fc2W[j];
    #pragma unroll
    for(int off=32;off;off>>=1) a+=__shfl_down(a,off,64);
    if(tid==0) out[g]=1.0f/(1.0f+expf(-(fc2b[0]+a)));
  }
}

extern "C" void kernel_launch(void* const* d_in, const int* in_sizes, int n_in,
                              void* d_out, int out_size, void* d_ws, size_t ws_size,
                              hipStream_t stream) {
  const float* x    = (const float*)d_in[0];
  const int*   ei   = (const int*)d_in[1];
  // d_in[2] = batch (unused; graphs are equal-size, contiguous)
  const float* W1   = (const float*)d_in[3];
  const float* b1   = (const float*)d_in[4];
  const float* p1   = (const float*)d_in[5];
  const float* W2   = (const float*)d_in[6];
  const float* b2   = (const float*)d_in[7];
  const float* p2   = (const float*)d_in[8];
  const float* fc1W = (const float*)d_in[9];
  const float* fc1b = (const float*)d_in[10];
  const float* fc2W = (const float*)d_in[11];
  const float* fc2b = (const float*)d_in[12];
  float* outp = (float*)d_out;

  gnn_fused<<<BGR, NT, 0, stream>>>(x, ei, W1, b1, p1, W2, b2, p2,
                                    fc1W, fc1b, fc2W, fc2b, outp);
}

// Round 11
// 75.717 us; speedup vs baseline: 1.0196x; 1.0196x over previous
//
#include <hip/hip_runtime.h>
#include <math.h>

constexpr int BGR=1024, NN=128, EG=2048, FIN=30, H1=30, H2=50, K1=103, K2=83, FCW=100;
constexpr int NT=512;
constexpr int EPT=EG/NT;      // 4 packed edges/thread
constexpr int EGP=EG+NN*4;    // padded CSR capacity (deg rounded to x4)
constexpr int XBSZ=NN*32;     // 16 KB node buffer, chunk-rotated swizzle
// row s, feature i -> dword s*32 + (((i>>2)+s)&7)*4 + (i&3)

__device__ __forceinline__ void row_fma4(const float* XB, int s, float w, int cq,
                                         float4&a0, float4&a1, float4&a2, float4&a3){
  int b=s<<5, r=s&7;
  float4 v0=*(const float4*)&XB[b+(((cq  +r)&7)<<2)];
  float4 v1=*(const float4*)&XB[b+(((cq+1+r)&7)<<2)];
  float4 v2=*(const float4*)&XB[b+(((cq+2+r)&7)<<2)];
  float4 v3=*(const float4*)&XB[b+(((cq+3+r)&7)<<2)];
  a0.x=fmaf(w,v0.x,a0.x); a0.y=fmaf(w,v0.y,a0.y); a0.z=fmaf(w,v0.z,a0.z); a0.w=fmaf(w,v0.w,a0.w);
  a1.x=fmaf(w,v1.x,a1.x); a1.y=fmaf(w,v1.y,a1.y); a1.z=fmaf(w,v1.z,a1.z); a1.w=fmaf(w,v1.w,a1.w);
  a2.x=fmaf(w,v2.x,a2.x); a2.y=fmaf(w,v2.y,a2.y); a2.z=fmaf(w,v2.z,a2.z); a2.w=fmaf(w,v2.w,a2.w);
  a3.x=fmaf(w,v3.x,a3.x); a3.y=fmaf(w,v3.y,a3.y); a3.z=fmaf(w,v3.z,a3.z); a3.w=fmaf(w,v3.w,a3.w);
}

__global__ __launch_bounds__(NT,8) void gnn_fused(
    const float* __restrict__ x, const int* __restrict__ ei,
    const float* __restrict__ W1, const float* __restrict__ b1, const float* __restrict__ p1,
    const float* __restrict__ W2, const float* __restrict__ b2, const float* __restrict__ p2,
    const float* __restrict__ fc1W, const float* __restrict__ fc1b,
    const float* __restrict__ fc2W, const float* __restrict__ fc2b,
    float* __restrict__ out)
{
  const int g=blockIdx.x, tid=threadIdx.x, lane=tid&63, wv=tid>>6;
  const int qd=wv&3;                               // wave-uniform quad class
  const int qdu=__builtin_amdgcn_readfirstlane(qd);
  const int hf=qdu>>1, ep=qdu&1;                   // feature half, edge parity
  const int cq=hf<<2;                              // first of 4 chunks
  const int nG=(wv>>2)*64+lane;                    // node 0..127

  __shared__ float XB[XBSZ];
  __shared__ unsigned char eord[EGP];
  __shared__ int cur[NN];
  __shared__ short cstart[NN];
  __shared__ float dsc[NN];                        // dinv1->score1->dinv2->score2
  __shared__ signed char rmap[NN], rm2[NN];
  __shared__ float sd[4*NN];
  __shared__ float pmx[8*13], psm[8*13], pol[2*H2], zfc[FCW];
  __shared__ int sh_wtot;

  // ---- packed edges in registers: src | dst<<8 ----
  int epk[EPT];
  {
    const int* srcg=ei+(size_t)g*EG;
    const int* dstg=ei+(size_t)BGR*EG+(size_t)g*EG;
    #pragma unroll
    for(int j=0;j<EPT;j++){ int e=tid+j*NT; epk[j]=(srcg[e]&127)|((dstg[e]&127)<<8); }
  }
  // ---- stage x swizzled; zero chunk-7 pads ----
  for(int l2=tid;l2<NN*15;l2+=NT){
    int n=l2/15, i=(l2-n*15)*2;
    float2 v=*(const float2*)&x[(size_t)g*NN*FIN+n*FIN+i];
    *(float2*)&XB[(n<<5)+((((i>>2)+n)&7)<<2)+(i&3)]=v;
  }
  if(tid<NN){ int o=(tid<<5)+(((7+tid)&7)<<2); XB[o+2]=0.f; XB[o+3]=0.f; cur[tid]=0; }
  __syncthreads();

  // ================= CSR build 1 (pad4) =================
  #pragma unroll
  for(int j=0;j<EPT;j++) atomicAdd(&cur[epk[j]>>8],1);
  __syncthreads();
  {
    int mydeg=(tid<NN)?cur[tid]:0;
    int mydeg4=(mydeg+3)&~3;
    int v=mydeg4;
    #pragma unroll
    for(int off=1;off<64;off<<=1){ int t=__shfl_up(v,off,64); if(lane>=off)v+=t; }
    if(tid==63) sh_wtot=v;
    for(int l=tid;l<EGP/4;l+=NT) ((int*)eord)[l]=-1;   // holes 0xFF
    __syncthreads();
    if(tid<NN){
      int start=v-mydeg4+((tid>=64)?sh_wtot:0);
      cur[tid]=start; cstart[tid]=(short)start;
      dsc[tid]=1.0f/sqrtf((float)mydeg+1.0f);          // dinv1
    }
  }
  __syncthreads();
  #pragma unroll
  for(int j=0;j<EPT;j++){ int p=atomicAdd(&cur[epk[j]>>8],1); eord[p]=(unsigned char)(epk[j]&255); }
  __syncthreads();

  // ---- prescale x by dinv1 (thread scales chunks 2qd, 2qd+1 of own row) ----
  {
    float di=dsc[nG];
    int b=nG<<5, r=nG&7;
    float4* q0=(float4*)&XB[b+((((2*qdu  )+r)&7)<<2)];
    float4* q1=(float4*)&XB[b+((((2*qdu+1)+r)&7)<<2)];
    float4 v0=*q0, v1=*q1;
    v0.x*=di; v0.y*=di; v0.z*=di; v0.w*=di;
    v1.x*=di; v1.y*=di; v1.z*=di; v1.w*=di;
    *q0=v0; *q1=v1;
  }
  __syncthreads();

  // ================= gather1: parity-split row-sum =================
  float4 a0={0,0,0,0},a1={0,0,0,0},a2={0,0,0,0},a3={0,0,0,0};
  {
    int e0=cstart[nG], deg=cur[nG]-(int)cstart[nG];
    int kend=e0+((deg+3)&~3);
    for(int k=e0;k<kend;k+=4){
      uchar4 ss=*(const uchar4*)&eord[k];
      int s0=ep? ss.y : ss.x;
      int s1=ep? ss.w : ss.z;
      row_fma4(XB,s0&127,(s0<128)?1.f:0.f,cq,a0,a1,a2,a3);
      row_fma4(XB,s1&127,(s1<128)?1.f:0.f,cq,a0,a1,a2,a3);
    }
    if(!ep) row_fma4(XB,nG,1.f,cq,a0,a1,a2,a3);        // self (cn == dinv fold)
  }
  __syncthreads();                                      // all x' reads done
  if(ep){                                               // write parity-1 partial
    int b=nG<<5, r=nG&7;
    *(float4*)&XB[b+(((cq  +r)&7)<<2)]=a0;
    *(float4*)&XB[b+(((cq+1+r)&7)<<2)]=a1;
    *(float4*)&XB[b+(((cq+2+r)&7)<<2)]=a2;
    *(float4*)&XB[b+(((cq+3+r)&7)<<2)]=a3;
  }
  __syncthreads();
  if(!ep){                                              // merge + finalize agg1
    float di=dsc[nG];
    int b=nG<<5, r=nG&7;
    float4* q0=(float4*)&XB[b+(((cq  +r)&7)<<2)];
    float4* q1=(float4*)&XB[b+(((cq+1+r)&7)<<2)];
    float4* q2=(float4*)&XB[b+(((cq+2+r)&7)<<2)];
    float4* q3=(float4*)&XB[b+(((cq+3+r)&7)<<2)];
    float4 v0=*q0,v1=*q1,v2=*q2,v3=*q3;
    v0.x=(v0.x+a0.x)*di; v0.y=(v0.y+a0.y)*di; v0.z=(v0.z+a0.z)*di; v0.w=(v0.w+a0.w)*di;
    v1.x=(v1.x+a1.x)*di; v1.y=(v1.y+a1.y)*di; v1.z=(v1.z+a1.z)*di; v1.w=(v1.w+a1.w)*di;
    v2.x=(v2.x+a2.x)*di; v2.y=(v2.y+a2.y)*di; v2.z=(v2.z+a2.z)*di; v2.w=(v2.w+a2.w)*di;
    v3.x=(v3.x+a3.x)*di; v3.y=(v3.y+a3.y)*di; v3.z=(v3.z+a3.z)*di; v3.w=(v3.w+a3.w)*di;
    *q0=v0; *q1=v1; *q2=v2; *q3=v3;
  }
  __syncthreads();                                      // agg1 ready

  // ================= mm1 (scalar W) + pool1 partial =================
  float h[8];
  {
    const int cnt1=(qdu<2)?8:7;
    const int bs1=qdu*8-((qdu==3)?1:0);
    const float* Wq=W1+bs1; const float* bq=b1+bs1; const float* pq=p1+bs1;
    #pragma unroll
    for(int jo=0;jo<8;jo++) h[jo]=(jo<cnt1)?bq[jo]:0.f;
    int b=nG<<5, r=nG&7;
    #pragma unroll
    for(int c=0;c<8;c++){
      float4 a=*(const float4*)&XB[b+(((c+r)&7)<<2)];
      #pragma unroll
      for(int e2=0;e2<4;e2++){
        int i=4*c+e2;
        if(i<FIN){
          float ai=(e2==0)?a.x:(e2==1)?a.y:(e2==2)?a.z:a.w;
          const float* wr=Wq+i*H1;
          #pragma unroll
          for(int jo=0;jo<8;jo++) if(jo<cnt1) h[jo]=fmaf(ai,wr[jo],h[jo]);
        }
      }
    }
    float dd=0.f;
    #pragma unroll
    for(int jo=0;jo<8;jo++) if(jo<cnt1){ h[jo]=fmaxf(h[jo],0.f); dd+=h[jo]*pq[jo]; }
    sd[qd*NN+nG]=dd;
  }
  __syncthreads();
  if(tid<NN){
    float nr=0.f;
    #pragma unroll
    for(int i=0;i<H1;i++){ float pv=p1[i]; nr+=pv*pv; }
    float dt=sd[tid]+sd[NN+tid]+sd[2*NN+tid]+sd[3*NN+tid];
    dsc[tid]=tanhf(dt/sqrtf(nr));                      // score1
  }
  __syncthreads();
  {  // rank1, 4-way split, stable == jax.lax.top_k
    int nR=tid>>2, sub=tid&3;
    float si=dsc[nR];
    int m0=sub<<5, rr=0;
    for(int m=m0;m<m0+32;m++){ float sm=dsc[m]; rr+=(sm>si)||(sm==si&&m<nR); }
    rr+=__shfl_xor(rr,1,64); rr+=__shfl_xor(rr,2,64);
    if(sub==0) rmap[nR]=(rr<K1)?(signed char)rr:(signed char)-1;
  }
  __syncthreads();
  {  // gated compact -> rank rows (score-gated; dinv2 folded later by prescale2)
    int rk=rmap[nG];
    if(rk>=0){
      float gv=dsc[nG];
      const int cnt1=(qdu<2)?8:7;
      const int bs1=qdu*8-((qdu==3)?1:0);
      #pragma unroll
      for(int j=0;j<8;j++) if(j<cnt1){
        int i=bs1+j;
        XB[(rk<<5)+((((i>>2)+rk)&7)<<2)+(i&3)]=h[j]*gv;
      }
    }
  }
  #pragma unroll
  for(int j=0;j<EPT;j++){
    int ns=rmap[epk[j]&255], nd=rmap[epk[j]>>8];
    epk[j]=((ns|nd)<0)? -1 : (ns|(nd<<8));
  }
  if(tid<NN) cur[tid]=0;
  __syncthreads();

  // ================= CSR build 2 (pruned, rank ids) =================
  #pragma unroll
  for(int j=0;j<EPT;j++) if(epk[j]>=0) atomicAdd(&cur[epk[j]>>8],1);
  __syncthreads();
  {
    int mydeg=(tid<K1)?cur[tid]:0;
    int mydeg4=(mydeg+3)&~3;
    int v=mydeg4;
    #pragma unroll
    for(int off=1;off<64;off<<=1){ int t=__shfl_up(v,off,64); if(lane>=off)v+=t; }
    if(tid==63) sh_wtot=v;
    for(int l=tid;l<EGP/4;l+=NT) ((int*)eord)[l]=-1;
    __syncthreads();
    if(tid<K1){
      int start=v-mydeg4+((tid>=64)?sh_wtot:0);
      cur[tid]=start; cstart[tid]=(short)start;
      dsc[tid]=1.0f/sqrtf((float)mydeg+1.0f);          // dinv2
    }
  }
  __syncthreads();
  #pragma unroll
  for(int j=0;j<EPT;j++) if(epk[j]>=0){ int p=atomicAdd(&cur[epk[j]>>8],1); eord[p]=(unsigned char)(epk[j]&255); }
  __syncthreads();

  // ---- prescale h1g rows by dinv2 ----
  if(nG<K1){
    float d2=dsc[nG];
    int b=nG<<5, r=nG&7;
    float4* q0=(float4*)&XB[b+((((2*qdu  )+r)&7)<<2)];
    float4* q1=(float4*)&XB[b+((((2*qdu+1)+r)&7)<<2)];
    float4 v0=*q0, v1=*q1;
    v0.x*=d2; v0.y*=d2; v0.z*=d2; v0.w*=d2;
    v1.x*=d2; v1.y*=d2; v1.z*=d2; v1.w*=d2;
    *q0=v0; *q1=v1;
  }
  __syncthreads();

  // ================= gather2: parity-split row-sum (pruned CSR) ==============
  a0=(float4){0,0,0,0}; a1=(float4){0,0,0,0}; a2=(float4){0,0,0,0}; a3=(float4){0,0,0,0};
  if(nG<K1){
    int e0=cstart[nG], deg=cur[nG]-(int)cstart[nG];
    int kend=e0+((deg+3)&~3);
    for(int k=e0;k<kend;k+=4){
      uchar4 ss=*(const uchar4*)&eord[k];
      int s0=ep? ss.y : ss.x;
      int s1=ep? ss.w : ss.z;
      row_fma4(XB,s0&127,(s0<128)?1.f:0.f,cq,a0,a1,a2,a3);
      row_fma4(XB,s1&127,(s1<128)?1.f:0.f,cq,a0,a1,a2,a3);
    }
    if(!ep) row_fma4(XB,nG,1.f,cq,a0,a1,a2,a3);
  }
  __syncthreads();
  if(ep && nG<K1){
    int b=nG<<5, r=nG&7;
    *(float4*)&XB[b+(((cq  +r)&7)<<2)]=a0;
    *(float4*)&XB[b+(((cq+1+r)&7)<<2)]=a1;
    *(float4*)&XB[b+(((cq+2+r)&7)<<2)]=a2;
    *(float4*)&XB[b+(((cq+3+r)&7)<<2)]=a3;
  }
  __syncthreads();
  if(!ep && nG<K1){
    float d2=dsc[nG];
    int b=nG<<5, r=nG&7;
    float4* q0=(float4*)&XB[b+(((cq  +r)&7)<<2)];
    float4* q1=(float4*)&XB[b+(((cq+1+r)&7)<<2)];
    float4* q2=(float4*)&XB[b+(((cq+2+r)&7)<<2)];
    float4* q3=(float4*)&XB[b+(((cq+3+r)&7)<<2)];
    float4 v0=*q0,v1=*q1,v2=*q2,v3=*q3;
    v0.x=(v0.x+a0.x)*d2; v0.y=(v0.y+a0.y)*d2; v0.z=(v0.z+a0.z)*d2; v0.w=(v0.w+a0.w)*d2;
    v1.x=(v1.x+a1.x)*d2; v1.y=(v1.y+a1.y)*d2; v1.z=(v1.z+a1.z)*d2; v1.w=(v1.w+a1.w)*d2;
    v2.x=(v2.x+a2.x)*d2; v2.y=(v2.y+a2.y)*d2; v2.z=(v2.z+a2.z)*d2; v2.w=(v2.w+a2.w)*d2;
    v3.x=(v3.x+a3.x)*d2; v3.y=(v3.y+a3.y)*d2; v3.z=(v3.z+a3.z)*d2; v3.w=(v3.w+a3.w)*d2;
    *q0=v0; *q1=v1; *q2=v2; *q3=v3;
  }
  __syncthreads();                                      // agg2 ready

  // ================= mm2 (scalar W) + pool2 partial =================
  float oc[13]={0,0,0,0,0,0,0,0,0,0,0,0,0};
  if(nG<K1){
    const int cnt2=(qdu<2)?13:12;
    const int bs2=qdu*13-((qdu==3)?1:0);
    const float* Wq=W2+bs2; const float* bq=b2+bs2; const float* pq=p2+bs2;
    #pragma unroll
    for(int jo=0;jo<13;jo++) oc[jo]=(jo<cnt2)?bq[jo]:0.f;
    int b=nG<<5, r=nG&7;
    #pragma unroll
    for(int c=0;c<8;c++){
      float4 a=*(const float4*)&XB[b+(((c+r)&7)<<2)];
      #pragma unroll
      for(int e2=0;e2<4;e2++){
        int i=4*c+e2;
        if(i<H1){
          float ai=(e2==0)?a.x:(e2==1)?a.y:(e2==2)?a.z:a.w;
          const float* wr=Wq+i*H2;
          #pragma unroll
          for(int jo=0;jo<13;jo++) if(jo<cnt2) oc[jo]=fmaf(ai,wr[jo],oc[jo]);
        }
      }
    }
    float dd=0.f;
    #pragma unroll
    for(int jo=0;jo<13;jo++) if(jo<cnt2){ oc[jo]=fmaxf(oc[jo],0.f); dd+=oc[jo]*pq[jo]; }
    sd[qd*NN+nG]=dd;
  }
  __syncthreads();
  if(tid<K1){
    float nr=0.f;
    #pragma unroll
    for(int i=0;i<H2;i++){ float pv=p2[i]; nr+=pv*pv; }
    float dt=sd[tid]+sd[NN+tid]+sd[2*NN+tid]+sd[3*NN+tid];
    dsc[tid]=tanhf(dt/sqrtf(nr));                      // score2
  }
  __syncthreads();
  {  // rank2 (4-way split, keep flag)
    int nR=tid>>2, sub=tid&3;
    float si=(nR<K1)?dsc[nR]:0.f;
    int m0=sub*26, m1=m0+26; if(m1>K1)m1=K1;
    int rr=0;
    for(int m=m0;m<m1;m++){ float sm=dsc[m]; rr+=(sm>si)||(sm==si&&m<nR); }
    rr+=__shfl_xor(rr,1,64); rr+=__shfl_xor(rr,2,64);
    if(sub==0 && nR<K1) rm2[nR]=(rr<K2)?(signed char)1:(signed char)-1;
  }
  __syncthreads();

  // ================= gated global max/mean =================
  {
    bool kept=(nG<K1)&&(rm2[nG]>0);
    float gv=kept?dsc[nG]:0.f;
    float mx[13], sm[13];
    #pragma unroll
    for(int j=0;j<13;j++){
      float v=kept? oc[j]*gv : 0.f;
      sm[j]=v; mx[j]=kept? v : -3.4e38f;
    }
    #pragma unroll
    for(int off=1;off<64;off<<=1){
      #pragma unroll
      for(int j=0;j<13;j++){
        mx[j]=fmaxf(mx[j],__shfl_xor(mx[j],off,64));
        sm[j]+=__shfl_xor(sm[j],off,64);
      }
    }
    if(lane==0){
      #pragma unroll
      for(int j=0;j<13;j++){ pmx[wv*13+j]=mx[j]; psm[wv*13+j]=sm[j]; }
    }
  }
  __syncthreads();
  if(tid<H2){
    int q=(tid<13)?0:(tid<26)?1:(tid<38)?2:3;
    int j=tid-(q*13-((q==3)?1:0));
    float m=fmaxf(pmx[q*13+j], pmx[(q+4)*13+j]);
    float s=psm[q*13+j]+psm[(q+4)*13+j];
    pol[tid]=m; pol[H2+tid]=s*(1.0f/(float)K2);
  }
  __syncthreads();

  // ================= fc1 + fc2 =================
  if(tid<FCW){
    float acc=fc1b[tid];
    #pragma unroll 4
    for(int i=0;i<2*H2;i++) acc+=pol[i]*fc1W[i*FCW+tid];
    zfc[tid]=fmaxf(acc,0.f);
  }
  __syncthreads();
  if(tid<64){
    float a=0.f;
    for(int j=tid;j<FCW;j+=64) a+=zfc[j]*fc2W[j];
    #pragma unroll
    for(int off=32;off;off>>=1) a+=__shfl_down(a,off,64);
    if(tid==0) out[g]=1.0f/(1.0f+expf(-(fc2b[0]+a)));
  }
}

extern "C" void kernel_launch(void* const* d_in, const int* in_sizes, int n_in,
                              void* d_out, int out_size, void* d_ws, size_t ws_size,
                              hipStream_t stream) {
  const float* x    = (const float*)d_in[0];
  const int*   ei   = (const int*)d_in[1];
  // d_in[2] = batch (unused; graphs are equal-size, contiguous)
  const float* W1   = (const float*)d_in[3];
  const float* b1   = (const float*)d_in[4];
  const float* p1   = (const float*)d_in[5];
  const float* W2   = (const float*)d_in[6];
  const float* b2   = (const float*)d_in[7];
  const float* p2   = (const float*)d_in[8];
  const float* fc1W = (const float*)d_in[9];
  const float* fc1b = (const float*)d_in[10];
  const float* fc2W = (const float*)d_in[11];
  const float* fc2b = (const float*)d_in[12];
  float* outp = (float*)d_out;

  gnn_fused<<<BGR, NT, 0, stream>>>(x, ei, W1, b1, p1, W2, b2, p2,
                                    fc1W, fc1b, fc2W, fc2b, outp);
}

// Round 12
// 60.812 us; speedup vs baseline: 1.2695x; 1.2451x over previous
//
#include <hip/hip_runtime.h>
#include <math.h>

constexpr int BGR=1024, NN=128, EG=2048, FIN=30, H1=30, H2=50, K1=103, K2=83, FCW=100;
constexpr int NT=256;
constexpr int EPT=EG/NT;          // 8 packed edges/thread
constexpr int EGP=EG+NN*4;        // padded CSR capacity (deg rounded to x4)
constexpr int SA=36;
constexpr int XBSZ=(NN+1)*32;     // 129 rows; row 128 = zero row (pad sentinel 0x80)
constexpr int AGSZ=NN*SA;
// AGG tail scratch (rows >=104 free: dwords 3744..4607)
constexpr int SD0=3744, PMX=4000, PSM=4100, POL=4200, ZFC=4300;

// row s, feature i -> dword s*32 + (((i>>2)+s)&7)*4 + (i&3)
__device__ __forceinline__ void row_add4(const float* XB, int s, int cq,
                                         float4&a0, float4&a1, float4&a2, float4&a3){
  int b=s<<5, r=s&7;
  float4 v0=*(const float4*)&XB[b+(((cq  +r)&7)<<2)];
  float4 v1=*(const float4*)&XB[b+(((cq+1+r)&7)<<2)];
  float4 v2=*(const float4*)&XB[b+(((cq+2+r)&7)<<2)];
  float4 v3=*(const float4*)&XB[b+(((cq+3+r)&7)<<2)];
  a0.x+=v0.x; a0.y+=v0.y; a0.z+=v0.z; a0.w+=v0.w;
  a1.x+=v1.x; a1.y+=v1.y; a1.z+=v1.z; a1.w+=v1.w;
  a2.x+=v2.x; a2.y+=v2.y; a2.z+=v2.z; a2.w+=v2.w;
  a3.x+=v3.x; a3.y+=v3.y; a3.z+=v3.z; a3.w+=v3.w;
}

__global__ __launch_bounds__(NT,4) void gnn_fused(
    const float* __restrict__ x, const int* __restrict__ ei,
    const float* __restrict__ W1, const float* __restrict__ b1, const float* __restrict__ p1,
    const float* __restrict__ W2, const float* __restrict__ b2, const float* __restrict__ p2,
    const float* __restrict__ fc1W, const float* __restrict__ fc1b,
    const float* __restrict__ fc2W, const float* __restrict__ fc2b,
    float* __restrict__ out)
{
  const int g=blockIdx.x, tid=threadIdx.x, lane=tid&63, wv=tid>>6;
  const int hf=wv&1;                         // wave-uniform feature half
  const int nG=(tid>>7)*64+lane;             // node: waves{0,1}->0..63, {2,3}->64..127
  const int hfu=__builtin_amdgcn_readfirstlane(hf);
  const int cq=hfu<<2;                       // first of this half's 4 chunks

  __shared__ float XB[XBSZ];
  __shared__ float AGG[AGSZ];
  __shared__ unsigned char eord[EGP];
  __shared__ int cur[NN];
  __shared__ short cstart[NN];
  __shared__ float dsc[NN];                  // dinv1->score1->dinv2->score2
  __shared__ signed char rmap[NN];
  __shared__ int sh_wtot;

  // ---- packed edges in registers: src | dst<<8 ----
  int epk[EPT];
  {
    const int* srcg=ei+(size_t)g*EG;
    const int* dstg=ei+(size_t)BGR*EG+(size_t)g*EG;
    #pragma unroll
    for(int j=0;j<EPT;j++){ int e=tid+j*NT; epk[j]=(srcg[e]&127)|((dstg[e]&127)<<8); }
  }
  // ---- stage x swizzled; zero chunk-7 pads; zero row 128 ----
  for(int l2=tid;l2<NN*15;l2+=NT){
    int n=l2/15, i=(l2-n*15)*2;
    float2 v=*(const float2*)&x[(size_t)g*NN*FIN+n*FIN+i];
    *(float2*)&XB[(n<<5)+((((i>>2)+n)&7)<<2)+(i&3)]=v;
  }
  if(tid<NN){ int o=(tid<<5)+(((7+tid)&7)<<2); XB[o+2]=0.f; XB[o+3]=0.f; cur[tid]=0; }
  if(tid>=NN && tid<NN+32) XB[NN*32+(tid-NN)]=0.f;
  __syncthreads();

  // ================= CSR build 1 (pad4, sentinel row 128) =================
  #pragma unroll
  for(int j=0;j<EPT;j++) atomicAdd(&cur[epk[j]>>8],1);
  __syncthreads();
  {
    int mydeg=(tid<NN)?cur[tid]:0;
    int mydeg4=(mydeg+3)&~3;
    int v=mydeg4;
    #pragma unroll
    for(int off=1;off<64;off<<=1){ int t=__shfl_up(v,off,64); if(lane>=off)v+=t; }
    if(tid==63) sh_wtot=v;
    for(int l=tid;l<EGP/4;l+=NT) ((int*)eord)[l]=0x80808080;   // holes -> zero row
    __syncthreads();
    if(tid<NN){
      int start=v-mydeg4+((tid>=64)?sh_wtot:0);
      cur[tid]=start; cstart[tid]=(short)start;
      dsc[tid]=1.0f/sqrtf((float)mydeg+1.0f);                  // dinv1
    }
  }
  __syncthreads();
  #pragma unroll
  for(int j=0;j<EPT;j++){ int p=atomicAdd(&cur[epk[j]>>8],1); eord[p]=(unsigned char)(epk[j]&255); }
  __syncthreads();

  // ---- prescale x by dinv1 (thread scales its half's 4 chunks of own row) ----
  {
    float di=dsc[nG];
    int b=nG<<5, r=nG&7;
    #pragma unroll
    for(int c=0;c<4;c++){
      float4* q=(float4*)&XB[b+((((cq+c)+r)&7)<<2)];
      float4 v=*q;
      v.x*=di; v.y*=di; v.z*=di; v.w*=di;
      *q=v;
    }
  }
  __syncthreads();

  // ================= gather1: pure row-sum, final x dinv1 ====================
  {
    float4 a0={0,0,0,0},a1={0,0,0,0},a2={0,0,0,0},a3={0,0,0,0};
    int e0=cstart[nG], deg=cur[nG]-e0;
    int kend=e0+((deg+3)&~3);
    for(int k=e0;k<kend;k+=4){
      uchar4 ss=*(const uchar4*)&eord[k];
      row_add4(XB,ss.x,cq,a0,a1,a2,a3);
      row_add4(XB,ss.y,cq,a0,a1,a2,a3);
      row_add4(XB,ss.z,cq,a0,a1,a2,a3);
      row_add4(XB,ss.w,cq,a0,a1,a2,a3);
    }
    row_add4(XB,nG,cq,a0,a1,a2,a3);          // self: dinv*(... + x'[n])
    float di=dsc[nG];
    a0.x*=di; a0.y*=di; a0.z*=di; a0.w*=di;
    a1.x*=di; a1.y*=di; a1.z*=di; a1.w*=di;
    a2.x*=di; a2.y*=di; a2.z*=di; a2.w*=di;
    a3.x*=di; a3.y*=di; a3.z*=di; a3.w*=di;
    float* dp=&AGG[nG*SA + (hfu<<4)];        // half0 -> feats 0..15, half1 -> 16..29
    ((float4*)dp)[0]=a0; ((float4*)dp)[1]=a1; ((float4*)dp)[2]=a2;
    if(!hfu) ((float4*)dp)[3]=a3;
    else     *(float2*)(dp+12)=make_float2(a3.x,a3.y);
  }
  __syncthreads();                 // x' dead; agg1 ready

  // ================= mm1: scalar-W (wave-uniform) ============================
  float h[15];
  {
    float A[30];
    {
      const float* arow=&AGG[nG*SA];
      float4 t0=((const float4*)arow)[0],t1=((const float4*)arow)[1],t2=((const float4*)arow)[2],
             t3=((const float4*)arow)[3],t4=((const float4*)arow)[4],t5=((const float4*)arow)[5],
             t6=((const float4*)arow)[6];
      float2 t7=*(const float2*)(arow+28);
      A[0]=t0.x;A[1]=t0.y;A[2]=t0.z;A[3]=t0.w; A[4]=t1.x;A[5]=t1.y;A[6]=t1.z;A[7]=t1.w;
      A[8]=t2.x;A[9]=t2.y;A[10]=t2.z;A[11]=t2.w; A[12]=t3.x;A[13]=t3.y;A[14]=t3.z;A[15]=t3.w;
      A[16]=t4.x;A[17]=t4.y;A[18]=t4.z;A[19]=t4.w; A[20]=t5.x;A[21]=t5.y;A[22]=t5.z;A[23]=t5.w;
      A[24]=t6.x;A[25]=t6.y;A[26]=t6.z;A[27]=t6.w; A[28]=t7.x;A[29]=t7.y;
    }
    const float* W1u=W1+hfu*15;
    const float* b1u=b1+hfu*15;
    #pragma unroll
    for(int jo=0;jo<15;jo++) h[jo]=b1u[jo];
    #pragma unroll
    for(int i=0;i<FIN;i++){
      float ai=A[i];
      #pragma unroll
      for(int jo=0;jo<15;jo++) h[jo]=fmaf(ai,W1u[i*H1+jo],h[jo]);
    }
    #pragma unroll
    for(int jo=0;jo<15;jo++) h[jo]=fmaxf(h[jo],0.f);
  }

  // ---- pool1 partial score (per half) ----
  {
    const float* p1u=p1+hfu*15;
    float d=0.f;
    #pragma unroll
    for(int jo=0;jo<15;jo++) d += h[jo]*p1u[jo];
    AGG[SD0 + hf*128 + nG]=d;
  }
  __syncthreads();
  if(tid<NN){
    float nr=0.f;
    #pragma unroll
    for(int i=0;i<H1;i++){ float pv=p1[i]; nr+=pv*pv; }
    float dt=AGG[SD0+tid]+AGG[SD0+128+tid];
    dsc[tid]=tanhf(dt/sqrtf(nr));            // score1
  }
  __syncthreads();
  {  // stable rank (pair-split) == jax.lax.top_k order
    int nR=tid>>1, hR=tid&1;
    float si=dsc[nR];
    int m0=hR<<6, r=0;
    for(int m=m0;m<m0+64;m++){ float sm=dsc[m]; r += (sm>si)||(sm==si&&m<nR); }
    r += __shfl_xor(r,1,64);
    if(!hR) rmap[nR]=(r<K1)?(signed char)r:(signed char)-1;
  }
  __syncthreads();
  {  // gated compact -> swizzled XB rank rows (score only; dinv2 folded later)
    int r=rmap[nG];
    if(r>=0){
      float gv=dsc[nG];
      #pragma unroll
      for(int j=0;j<15;j++){
        int i=hfu*15+j;
        XB[(r<<5)+((((i>>2)+r)&7)<<2)+(i&3)]=h[j]*gv;
      }
    }
  }
  #pragma unroll
  for(int j=0;j<EPT;j++){
    int ns=rmap[epk[j]&255], nd=rmap[epk[j]>>8];
    epk[j]=((ns|nd)<0)? -1 : (ns|(nd<<8));
  }
  if(tid<K1) cur[tid]=0;
  __syncthreads();

  // ================= CSR build 2 (pruned, rank ids) =================
  #pragma unroll
  for(int j=0;j<EPT;j++) if(epk[j]>=0) atomicAdd(&cur[epk[j]>>8],1);
  __syncthreads();
  {
    int mydeg=(tid<K1)?cur[tid]:0;
    int mydeg4=(mydeg+3)&~3;
    int v=mydeg4;
    #pragma unroll
    for(int off=1;off<64;off<<=1){ int t=__shfl_up(v,off,64); if(lane>=off)v+=t; }
    if(tid==63) sh_wtot=v;
    for(int l=tid;l<EGP/4;l+=NT) ((int*)eord)[l]=0x80808080;
    __syncthreads();
    if(tid<K1){
      int start=v-mydeg4+((tid>=64)?sh_wtot:0);
      cur[tid]=start; cstart[tid]=(short)start;
      dsc[tid]=1.0f/sqrtf((float)mydeg+1.0f);            // dinv2
    }
  }
  __syncthreads();
  #pragma unroll
  for(int j=0;j<EPT;j++) if(epk[j]>=0){ int p=atomicAdd(&cur[epk[j]>>8],1); eord[p]=(unsigned char)(epk[j]&255); }
  __syncthreads();

  // ---- prescale2: scale rank rows by dinv2 ----
  if(nG<K1){
    float d2=dsc[nG];
    int b=nG<<5, r=nG&7;
    #pragma unroll
    for(int c=0;c<4;c++){
      float4* q=(float4*)&XB[b+((((cq+c)+r)&7)<<2)];
      float4 v=*q;
      v.x*=d2; v.y*=d2; v.z*=d2; v.w*=d2;
      *q=v;
    }
  }
  __syncthreads();

  // ================= gather2: pure row-sum (pruned CSR), final x dinv2 =======
  if(nG<K1){
    float4 a0={0,0,0,0},a1={0,0,0,0},a2={0,0,0,0},a3={0,0,0,0};
    int e0=cstart[nG], deg=cur[nG]-e0;
    int kend=e0+((deg+3)&~3);
    for(int k=e0;k<kend;k+=4){
      uchar4 ss=*(const uchar4*)&eord[k];
      row_add4(XB,ss.x,cq,a0,a1,a2,a3);
      row_add4(XB,ss.y,cq,a0,a1,a2,a3);
      row_add4(XB,ss.z,cq,a0,a1,a2,a3);
      row_add4(XB,ss.w,cq,a0,a1,a2,a3);
    }
    row_add4(XB,nG,cq,a0,a1,a2,a3);
    float d2=dsc[nG];
    a0.x*=d2; a0.y*=d2; a0.z*=d2; a0.w*=d2;
    a1.x*=d2; a1.y*=d2; a1.z*=d2; a1.w*=d2;
    a2.x*=d2; a2.y*=d2; a2.z*=d2; a2.w*=d2;
    a3.x*=d2; a3.y*=d2; a3.z*=d2; a3.w*=d2;
    float* dp=&AGG[nG*SA + (hfu<<4)];
    ((float4*)dp)[0]=a0; ((float4*)dp)[1]=a1; ((float4*)dp)[2]=a2;
    if(!hfu) ((float4*)dp)[3]=a3;
    else     *(float2*)(dp+12)=make_float2(a3.x,a3.y);
  }
  __syncthreads();                 // agg2 ready

  // ================= mm2: scalar-W + pool2 partial ===========================
  float oc[25];
  if(nG<K1){
    float A[30];
    {
      const float* arow=&AGG[nG*SA];
      float4 t0=((const float4*)arow)[0],t1=((const float4*)arow)[1],t2=((const float4*)arow)[2],
             t3=((const float4*)arow)[3],t4=((const float4*)arow)[4],t5=((const float4*)arow)[5],
             t6=((const float4*)arow)[6];
      float2 t7=*(const float2*)(arow+28);
      A[0]=t0.x;A[1]=t0.y;A[2]=t0.z;A[3]=t0.w; A[4]=t1.x;A[5]=t1.y;A[6]=t1.z;A[7]=t1.w;
      A[8]=t2.x;A[9]=t2.y;A[10]=t2.z;A[11]=t2.w; A[12]=t3.x;A[13]=t3.y;A[14]=t3.z;A[15]=t3.w;
      A[16]=t4.x;A[17]=t4.y;A[18]=t4.z;A[19]=t4.w; A[20]=t5.x;A[21]=t5.y;A[22]=t5.z;A[23]=t5.w;
      A[24]=t6.x;A[25]=t6.y;A[26]=t6.z;A[27]=t6.w; A[28]=t7.x;A[29]=t7.y;
    }
    const float* W2u=W2+hfu*25;
    const float* b2u=b2+hfu*25;
    #pragma unroll
    for(int jo=0;jo<25;jo++) oc[jo]=b2u[jo];
    #pragma unroll
    for(int i=0;i<H1;i++){
      float ai=A[i];
      #pragma unroll
      for(int jo=0;jo<25;jo++) oc[jo]=fmaf(ai,W2u[i*H2+jo],oc[jo]);
    }
    const float* p2u=p2+hfu*25;
    float d=0.f;
    #pragma unroll
    for(int jo=0;jo<25;jo++){ oc[jo]=fmaxf(oc[jo],0.f); d += oc[jo]*p2u[jo]; }
    AGG[SD0 + hf*128 + nG]=d;
  }
  __syncthreads();
  if(tid<K1){
    float nr=0.f;
    #pragma unroll
    for(int i=0;i<H2;i++){ float pv=p2[i]; nr+=pv*pv; }
    float dt=AGG[SD0+tid]+AGG[SD0+128+tid];
    dsc[tid]=tanhf(dt/sqrtf(nr));            // score2
  }
  __syncthreads();
  {  // rank2 (pair-split, keep flag)
    int nR=tid>>1, hR=tid&1;
    float si=(nR<K1)?dsc[nR]:0.f;
    int m0=hR?52:0, m1=hR?K1:52, r=0;
    for(int m=m0;m<m1;m++){ float sm=dsc[m]; r += (sm>si)||(sm==si&&m<nR); }
    r += __shfl_xor(r,1,64);
    if(!hR && nR<K1) rmap[nR]=(r<K2)?(signed char)1:(signed char)-1;
  }
  __syncthreads();

  // ================= gated global max/mean ===================================
  {
    bool kept=(nG<K1)&&(rmap[nG]>0);
    float gv=kept?dsc[nG]:0.f;
    float mx[25],sm[25];
    #pragma unroll
    for(int j=0;j<25;j++){ float v=oc[j]*gv; sm[j]=kept?v:0.f; mx[j]=kept?v:-3.4e38f; }
    #pragma unroll
    for(int off=1;off<64;off<<=1){
      #pragma unroll
      for(int j=0;j<25;j++){ mx[j]=fmaxf(mx[j],__shfl_xor(mx[j],off,64)); sm[j]+=__shfl_xor(sm[j],off,64); }
    }
    if(lane==0){
      #pragma unroll
      for(int j=0;j<25;j++){ AGG[PMX+wv*25+j]=mx[j]; AGG[PSM+wv*25+j]=sm[j]; }
    }
  }
  __syncthreads();
  if(tid<H2){
    int hfX=(tid>=25), j=tid-hfX*25;
    float m=fmaxf(AGG[PMX+hfX*25+j], AGG[PMX+(hfX+2)*25+j]);
    float s=AGG[PSM+hfX*25+j]+AGG[PSM+(hfX+2)*25+j];
    AGG[POL+tid]=m;
    AGG[POL+H2+tid]=s*(1.0f/(float)K2);
  }
  __syncthreads();

  // ================= fc1 + fc2 =================
  if(tid<FCW){
    float acc=fc1b[tid];
    #pragma unroll 4
    for(int i=0;i<2*H2;i++) acc += AGG[POL+i]*fc1W[i*FCW+tid];
    AGG[ZFC+tid]=fmaxf(acc,0.f);
  }
  __syncthreads();
  if(tid<64){
    float a=0.f;
    for(int j=tid;j<FCW;j+=64) a += AGG[ZFC+j]*fc2W[j];
    #pragma unroll
    for(int off=32;off;off>>=1) a += __shfl_down(a,off,64);
    if(tid==0) out[g]=1.0f/(1.0f+expf(-(fc2b[0]+a)));
  }
}

extern "C" void kernel_launch(void* const* d_in, const int* in_sizes, int n_in,
                              void* d_out, int out_size, void* d_ws, size_t ws_size,
                              hipStream_t stream) {
  const float* x    = (const float*)d_in[0];
  const int*   ei   = (const int*)d_in[1];
  // d_in[2] = batch (unused; graphs are equal-size, contiguous)
  const float* W1   = (const float*)d_in[3];
  const float* b1   = (const float*)d_in[4];
  const float* p1   = (const float*)d_in[5];
  const float* W2   = (const float*)d_in[6];
  const float* b2   = (const float*)d_in[7];
  const float* p2   = (const float*)d_in[8];
  const float* fc1W = (const float*)d_in[9];
  const float* fc1b = (const float*)d_in[10];
  const float* fc2W = (const float*)d_in[11];
  const float* fc2b = (const float*)d_in[12];
  float* outp = (float*)d_out;

  gnn_fused<<<BGR, NT, 0, stream>>>(x, ei, W1, b1, p1, W2, b2, p2,
                                    fc1W, fc1b, fc2W, fc2b, outp);
}

// Round 14
// 50.806 us; speedup vs baseline: 1.5195x; 1.1970x over previous
//
#include <hip/hip_runtime.h>
#include <math.h>

constexpr int BGR=1024, NN=128, EG=2048, FIN=30, H1=30, H2=50, K1=103, K2=83, FCW=100;
constexpr int NT=256;
constexpr int EPT=EG/NT;          // 8 packed edges/thread
constexpr int EGP=EG+NN*4;        // padded CSR capacity (deg rounded to x4)
constexpr int SA=36;
constexpr int XBSZ=(NN+1)*32;     // 129 rows; row 128 = zero row (pad sentinel 0x80)
constexpr int AGSZ=NN*SA;         // 4608
// AGG-relative scratch (rows >=104 free: dwords 3744..4607)
constexpr int SD0=3744, POL=4200, ZFC=4304;
// FT: [103][51] gated-value buffer for pool scan; aliases SMEM[0..5252]
// (XB + AGG rows 0..31), all dead after mm2.

// row s, feature i -> dword s*32 + (((i>>2)+s)&7)*4 + (i&3)
__device__ __forceinline__ void row_add4(const float* XB, int s, int cq,
                                         float4&a0, float4&a1, float4&a2, float4&a3){
  int b=s<<5, r=s&7;
  float4 v0=*(const float4*)&XB[b+(((cq  +r)&7)<<2)];
  float4 v1=*(const float4*)&XB[b+(((cq+1+r)&7)<<2)];
  float4 v2=*(const float4*)&XB[b+(((cq+2+r)&7)<<2)];
  float4 v3=*(const float4*)&XB[b+(((cq+3+r)&7)<<2)];
  a0.x+=v0.x; a0.y+=v0.y; a0.z+=v0.z; a0.w+=v0.w;
  a1.x+=v1.x; a1.y+=v1.y; a1.z+=v1.z; a1.w+=v1.w;
  a2.x+=v2.x; a2.y+=v2.y; a2.z+=v2.z; a2.w+=v2.w;
  a3.x+=v3.x; a3.y+=v3.y; a3.z+=v3.z; a3.w+=v3.w;
}

__global__ __launch_bounds__(NT,4) void gnn_fused(
    const float* __restrict__ x, const int* __restrict__ ei,
    const float* __restrict__ W1, const float* __restrict__ b1, const float* __restrict__ p1,
    const float* __restrict__ W2, const float* __restrict__ b2, const float* __restrict__ p2,
    const float* __restrict__ fc1W, const float* __restrict__ fc1b,
    const float* __restrict__ fc2W, const float* __restrict__ fc2b,
    float* __restrict__ out)
{
  const int g=blockIdx.x, tid=threadIdx.x, lane=tid&63, wv=tid>>6;
  const int hf=wv&1;                         // wave-uniform feature half
  const int nG=(tid>>7)*64+lane;             // node: waves{0,1}->0..63, {2,3}->64..127
  const int hfu=__builtin_amdgcn_readfirstlane(hf);
  const int cq=hfu<<2;                       // first of this half's 4 chunks

  __shared__ __align__(16) float SMEM[XBSZ+AGSZ];
  float* XB  = SMEM;
  float* AGG = SMEM+XBSZ;
  float* FT  = SMEM;                          // pool buffer, aliases dead XB/AGG-front
  __shared__ unsigned char eord[EGP];
  __shared__ int cur[NN];
  __shared__ short cstart[NN];
  __shared__ float dsc[NN];                  // dinv1->score1->dinv2->score2
  __shared__ signed char rmap[NN];
  __shared__ int sh_wtot;

  // ---- packed edges in registers: src | dst<<8 ----
  int epk[EPT];
  {
    const int* srcg=ei+(size_t)g*EG;
    const int* dstg=ei+(size_t)BGR*EG+(size_t)g*EG;
    #pragma unroll
    for(int j=0;j<EPT;j++){ int e=tid+j*NT; epk[j]=(srcg[e]&127)|((dstg[e]&127)<<8); }
  }
  // ---- stage x swizzled; zero chunk-7 pads; zero row 128 ----
  for(int l2=tid;l2<NN*15;l2+=NT){
    int n=l2/15, i=(l2-n*15)*2;
    float2 v=*(const float2*)&x[(size_t)g*NN*FIN+n*FIN+i];
    *(float2*)&XB[(n<<5)+((((i>>2)+n)&7)<<2)+(i&3)]=v;
  }
  if(tid<NN){ int o=(tid<<5)+(((7+tid)&7)<<2); XB[o+2]=0.f; XB[o+3]=0.f; cur[tid]=0; }
  if(tid>=NN && tid<NN+32) XB[NN*32+(tid-NN)]=0.f;
  __syncthreads();

  // ================= CSR build 1 (pad4, sentinel row 128) =================
  #pragma unroll
  for(int j=0;j<EPT;j++) atomicAdd(&cur[epk[j]>>8],1);
  __syncthreads();
  {
    int mydeg=(tid<NN)?cur[tid]:0;
    int mydeg4=(mydeg+3)&~3;
    int v=mydeg4;
    #pragma unroll
    for(int off=1;off<64;off<<=1){ int t=__shfl_up(v,off,64); if(lane>=off)v+=t; }
    if(tid==63) sh_wtot=v;
    for(int l=tid;l<EGP/4;l+=NT) ((int*)eord)[l]=0x80808080;   // holes -> zero row
    __syncthreads();
    if(tid<NN){
      int start=v-mydeg4+((tid>=64)?sh_wtot:0);
      cur[tid]=start; cstart[tid]=(short)start;
      dsc[tid]=1.0f/sqrtf((float)mydeg+1.0f);                  // dinv1
    }
  }
  __syncthreads();
  #pragma unroll
  for(int j=0;j<EPT;j++){ int p=atomicAdd(&cur[epk[j]>>8],1); eord[p]=(unsigned char)(epk[j]&255); }
  __syncthreads();

  // ---- prescale x by dinv1 (thread scales its half's 4 chunks of own row) ----
  {
    float di=dsc[nG];
    int b=nG<<5, r=nG&7;
    #pragma unroll
    for(int c=0;c<4;c++){
      float4* q=(float4*)&XB[b+((((cq+c)+r)&7)<<2)];
      float4 v=*q;
      v.x*=di; v.y*=di; v.z*=di; v.w*=di;
      *q=v;
    }
  }
  __syncthreads();

  // ================= gather1: pure row-sum, final x dinv1 ====================
  {
    float4 a0={0,0,0,0},a1={0,0,0,0},a2={0,0,0,0},a3={0,0,0,0};
    int e0=cstart[nG], deg=cur[nG]-e0;
    int kend=e0+((deg+3)&~3);
    for(int k=e0;k<kend;k+=4){
      uchar4 ss=*(const uchar4*)&eord[k];
      row_add4(XB,ss.x,cq,a0,a1,a2,a3);
      row_add4(XB,ss.y,cq,a0,a1,a2,a3);
      row_add4(XB,ss.z,cq,a0,a1,a2,a3);
      row_add4(XB,ss.w,cq,a0,a1,a2,a3);
    }
    row_add4(XB,nG,cq,a0,a1,a2,a3);          // self: dinv*(... + x'[n])
    float di=dsc[nG];
    a0.x*=di; a0.y*=di; a0.z*=di; a0.w*=di;
    a1.x*=di; a1.y*=di; a1.z*=di; a1.w*=di;
    a2.x*=di; a2.y*=di; a2.z*=di; a2.w*=di;
    a3.x*=di; a3.y*=di; a3.z*=di; a3.w*=di;
    float* dp=&AGG[nG*SA + (hfu<<4)];        // half0 -> feats 0..15, half1 -> 16..29
    ((float4*)dp)[0]=a0; ((float4*)dp)[1]=a1; ((float4*)dp)[2]=a2;
    if(!hfu) ((float4*)dp)[3]=a3;
    else     *(float2*)(dp+12)=make_float2(a3.x,a3.y);
  }
  __syncthreads();                 // x' dead; agg1 ready

  // ================= mm1: scalar-W (wave-uniform) ============================
  float h[15];
  {
    float A[30];
    {
      const float* arow=&AGG[nG*SA];
      float4 t0=((const float4*)arow)[0],t1=((const float4*)arow)[1],t2=((const float4*)arow)[2],
             t3=((const float4*)arow)[3],t4=((const float4*)arow)[4],t5=((const float4*)arow)[5],
             t6=((const float4*)arow)[6];
      float2 t7=*(const float2*)(arow+28);
      A[0]=t0.x;A[1]=t0.y;A[2]=t0.z;A[3]=t0.w; A[4]=t1.x;A[5]=t1.y;A[6]=t1.z;A[7]=t1.w;
      A[8]=t2.x;A[9]=t2.y;A[10]=t2.z;A[11]=t2.w; A[12]=t3.x;A[13]=t3.y;A[14]=t3.z;A[15]=t3.w;
      A[16]=t4.x;A[17]=t4.y;A[18]=t4.z;A[19]=t4.w; A[20]=t5.x;A[21]=t5.y;A[22]=t5.z;A[23]=t5.w;
      A[24]=t6.x;A[25]=t6.y;A[26]=t6.z;A[27]=t6.w; A[28]=t7.x;A[29]=t7.y;
    }
    const float* W1u=W1+hfu*15;
    const float* b1u=b1+hfu*15;
    #pragma unroll
    for(int jo=0;jo<15;jo++) h[jo]=b1u[jo];
    #pragma unroll
    for(int i=0;i<FIN;i++){
      float ai=A[i];
      #pragma unroll
      for(int jo=0;jo<15;jo++) h[jo]=fmaf(ai,W1u[i*H1+jo],h[jo]);
    }
    #pragma unroll
    for(int jo=0;jo<15;jo++) h[jo]=fmaxf(h[jo],0.f);
  }

  // ---- pool1 partial score (per half) ----
  {
    const float* p1u=p1+hfu*15;
    float d=0.f;
    #pragma unroll
    for(int jo=0;jo<15;jo++) d += h[jo]*p1u[jo];
    AGG[SD0 + hf*128 + nG]=d;
  }
  __syncthreads();
  if(tid<NN){
    float nr=0.f;
    #pragma unroll
    for(int i=0;i<H1;i++){ float pv=p1[i]; nr+=pv*pv; }
    float dt=AGG[SD0+tid]+AGG[SD0+128+tid];
    dsc[tid]=tanhf(dt/sqrtf(nr));            // score1
  }
  __syncthreads();
  {  // stable rank (pair-split) == jax.lax.top_k order
    int nR=tid>>1, hR=tid&1;
    float si=dsc[nR];
    int m0=hR<<6, r=0;
    for(int m=m0;m<m0+64;m++){ float sm=dsc[m]; r += (sm>si)||(sm==si&&m<nR); }
    r += __shfl_xor(r,1,64);
    if(!hR) rmap[nR]=(r<K1)?(signed char)r:(signed char)-1;
  }
  __syncthreads();
  {  // gated compact -> swizzled XB rank rows (score only; dinv2 by prescale2)
    int r=rmap[nG];
    if(r>=0){
      float gv=dsc[nG];
      #pragma unroll
      for(int j=0;j<15;j++){
        int i=hfu*15+j;
        XB[(r<<5)+((((i>>2)+r)&7)<<2)+(i&3)]=h[j]*gv;
      }
    }
  }
  #pragma unroll
  for(int j=0;j<EPT;j++){
    int ns=rmap[epk[j]&255], nd=rmap[epk[j]>>8];
    epk[j]=((ns|nd)<0)? -1 : (ns|(nd<<8));
  }
  if(tid<K1) cur[tid]=0;
  __syncthreads();

  // ================= CSR build 2 (pruned, rank ids) =================
  #pragma unroll
  for(int j=0;j<EPT;j++) if(epk[j]>=0) atomicAdd(&cur[epk[j]>>8],1);
  __syncthreads();
  {
    int mydeg=(tid<K1)?cur[tid]:0;
    int mydeg4=(mydeg+3)&~3;
    int v=mydeg4;
    #pragma unroll
    for(int off=1;off<64;off<<=1){ int t=__shfl_up(v,off,64); if(lane>=off)v+=t; }
    if(tid==63) sh_wtot=v;
    for(int l=tid;l<EGP/4;l+=NT) ((int*)eord)[l]=0x80808080;
    __syncthreads();
    if(tid<K1){
      int start=v-mydeg4+((tid>=64)?sh_wtot:0);
      cur[tid]=start; cstart[tid]=(short)start;
      dsc[tid]=1.0f/sqrtf((float)mydeg+1.0f);            // dinv2 (by rank id)
    }
  }
  __syncthreads();
  #pragma unroll
  for(int j=0;j<EPT;j++) if(epk[j]>=0){ int p=atomicAdd(&cur[epk[j]>>8],1); eord[p]=(unsigned char)(epk[j]&255); }
  __syncthreads();

  // ---- prescale2: scale rank rows by dinv2 ----
  if(nG<K1){
    float d2=dsc[nG];
    int b=nG<<5, r=nG&7;
    #pragma unroll
    for(int c=0;c<4;c++){
      float4* q=(float4*)&XB[b+((((cq+c)+r)&7)<<2)];
      float4 v=*q;
      v.x*=d2; v.y*=d2; v.z*=d2; v.w*=d2;
      *q=v;
    }
  }
  __syncthreads();

  // ================= gather2: pure row-sum (pruned CSR), final x dinv2 =======
  if(nG<K1){
    float4 a0={0,0,0,0},a1={0,0,0,0},a2={0,0,0,0},a3={0,0,0,0};
    int e0=cstart[nG], deg=cur[nG]-e0;
    int kend=e0+((deg+3)&~3);
    for(int k=e0;k<kend;k+=4){
      uchar4 ss=*(const uchar4*)&eord[k];
      row_add4(XB,ss.x,cq,a0,a1,a2,a3);
      row_add4(XB,ss.y,cq,a0,a1,a2,a3);
      row_add4(XB,ss.z,cq,a0,a1,a2,a3);
      row_add4(XB,ss.w,cq,a0,a1,a2,a3);
    }
    row_add4(XB,nG,cq,a0,a1,a2,a3);
    float d2=dsc[nG];
    a0.x*=d2; a0.y*=d2; a0.z*=d2; a0.w*=d2;
    a1.x*=d2; a1.y*=d2; a1.z*=d2; a1.w*=d2;
    a2.x*=d2; a2.y*=d2; a2.z*=d2; a2.w*=d2;
    a3.x*=d2; a3.y*=d2; a3.z*=d2; a3.w*=d2;
    float* dp=&AGG[nG*SA + (hfu<<4)];
    ((float4*)dp)[0]=a0; ((float4*)dp)[1]=a1; ((float4*)dp)[2]=a2;
    if(!hfu) ((float4*)dp)[3]=a3;
    else     *(float2*)(dp+12)=make_float2(a3.x,a3.y);
  }
  __syncthreads();                 // agg2 ready

  // ================= mm2: scalar-W + pool2 partial ===========================
  float oc[25];
  if(nG<K1){
    float A[30];
    {
      const float* arow=&AGG[nG*SA];
      float4 t0=((const float4*)arow)[0],t1=((const float4*)arow)[1],t2=((const float4*)arow)[2],
             t3=((const float4*)arow)[3],t4=((const float4*)arow)[4],t5=((const float4*)arow)[5],
             t6=((const float4*)arow)[6];
      float2 t7=*(const float2*)(arow+28);
      A[0]=t0.x;A[1]=t0.y;A[2]=t0.z;A[3]=t0.w; A[4]=t1.x;A[5]=t1.y;A[6]=t1.z;A[7]=t1.w;
      A[8]=t2.x;A[9]=t2.y;A[10]=t2.z;A[11]=t2.w; A[12]=t3.x;A[13]=t3.y;A[14]=t3.z;A[15]=t3.w;
      A[16]=t4.x;A[17]=t4.y;A[18]=t4.z;A[19]=t4.w; A[20]=t5.x;A[21]=t5.y;A[22]=t5.z;A[23]=t5.w;
      A[24]=t6.x;A[25]=t6.y;A[26]=t6.z;A[27]=t6.w; A[28]=t7.x;A[29]=t7.y;
    }
    const float* W2u=W2+hfu*25;
    const float* b2u=b2+hfu*25;
    #pragma unroll
    for(int jo=0;jo<25;jo++) oc[jo]=b2u[jo];
    #pragma unroll
    for(int i=0;i<H1;i++){
      float ai=A[i];
      #pragma unroll
      for(int jo=0;jo<25;jo++) oc[jo]=fmaf(ai,W2u[i*H2+jo],oc[jo]);
    }
    const float* p2u=p2+hfu*25;
    float d=0.f;
    #pragma unroll
    for(int jo=0;jo<25;jo++){ oc[jo]=fmaxf(oc[jo],0.f); d += oc[jo]*p2u[jo]; }
    AGG[SD0 + hf*128 + nG]=d;
  }
  __syncthreads();
  if(tid<K1){
    float nr=0.f;
    #pragma unroll
    for(int i=0;i<H2;i++){ float pv=p2[i]; nr+=pv*pv; }
    float dt=AGG[SD0+tid]+AGG[SD0+128+tid];
    dsc[tid]=tanhf(dt/sqrtf(nr));            // score2
  }
  __syncthreads();
  {  // rank2 (pair-split, keep flag)
    int nR=tid>>1, hR=tid&1;
    float si=(nR<K1)?dsc[nR]:0.f;
    int m0=hR?52:0, m1=hR?K1:52, r=0;
    for(int m=m0;m<m1;m++){ float sm=dsc[m]; r += (sm>si)||(sm==si&&m<nR); }
    r += __shfl_xor(r,1,64);
    if(!hR && nR<K1) rmap[nR]=(r<K2)?(signed char)1:(signed char)-1;
  }
  __syncthreads();

  // ================= gated pool via FT column scan (XB/AGG-front dead) =======
  if(nG<K1){
    bool kept=rmap[nG]>0;
    float gv=kept?dsc[nG]:0.f;
    #pragma unroll
    for(int j=0;j<25;j++){
      FT[nG*51 + hfu*25 + j] = kept ? oc[j]*gv : -3.4e38f;
    }
  }
  __syncthreads();
  if(tid<H2){
    float mx=-3.4e38f, sm=0.f;
    for(int n=0;n<K1;n++){
      float v=FT[n*51+tid];
      mx=fmaxf(mx,v);
      sm += (v>-1.0e30f)? v : 0.f;
    }
    AGG[POL+tid]=mx;
    AGG[POL+H2+tid]=sm*(1.0f/(float)K2);
  }
  __syncthreads();

  // ================= fc1 (float4 pol reads) + fc2 =================
  if(tid<FCW){
    float acc=fc1b[tid];
    #pragma unroll
    for(int i4=0;i4<25;i4++){
      float4 pv=*(const float4*)&AGG[POL+i4*4];
      int i=i4*4;
      acc=fmaf(pv.x,fc1W[(i  )*FCW+tid],acc);
      acc=fmaf(pv.y,fc1W[(i+1)*FCW+tid],acc);
      acc=fmaf(pv.z,fc1W[(i+2)*FCW+tid],acc);
      acc=fmaf(pv.w,fc1W[(i+3)*FCW+tid],acc);
    }
    AGG[ZFC+tid]=fmaxf(acc,0.f);
  }
  __syncthreads();
  if(tid<64){
    float a=0.f;
    for(int j=tid;j<FCW;j+=64) a += AGG[ZFC+j]*fc2W[j];
    #pragma unroll
    for(int off=32;off;off>>=1) a += __shfl_down(a,off,64);
    if(tid==0) out[g]=1.0f/(1.0f+expf(-(fc2b[0]+a)));
  }
}

extern "C" void kernel_launch(void* const* d_in, const int* in_sizes, int n_in,
                              void* d_out, int out_size, void* d_ws, size_t ws_size,
                              hipStream_t stream) {
  const float* x    = (const float*)d_in[0];
  const int*   ei   = (const int*)d_in[1];
  // d_in[2] = batch (unused; graphs are equal-size, contiguous)
  const float* W1   = (const float*)d_in[3];
  const float* b1   = (const float*)d_in[4];
  const float* p1   = (const float*)d_in[5];
  const float* W2   = (const float*)d_in[6];
  const float* b2   = (const float*)d_in[7];
  const float* p2   = (const float*)d_in[8];
  const float* fc1W = (const float*)d_in[9];
  const float* fc1b = (const float*)d_in[10];
  const float* fc2W = (const float*)d_in[11];
  const float* fc2b = (const float*)d_in[12];
  float* outp = (float*)d_out;

  gnn_fused<<<BGR, NT, 0, stream>>>(x, ei, W1, b1, p1, W2, b2, p2,
                                    fc1W, fc1b, fc2W, fc2b, outp);
}

// Round 15
// 49.159 us; speedup vs baseline: 1.5704x; 1.0335x over previous
//
#include <hip/hip_runtime.h>
#include <math.h>

constexpr int BGR=1024, NN=128, EG=2048, FIN=30, H1=30, H2=50, K1=103, K2=83, FCW=100;
constexpr int NT=256;
constexpr int EPT=EG/NT;          // 8 packed edges/thread
constexpr int EGP=EG+NN*4;        // padded CSR capacity (deg rounded to x4)
constexpr int SA=36;
constexpr int XBSZ=(NN+1)*32;     // 129 rows; row 128 = zero row (pad sentinel 0x80)
constexpr int AGSZ=NN*SA;         // 4608
// AGG-relative scratch (rows >=104 free: dwords 3744..4607)
constexpr int SD0=3744, POL=4200, ZFC=4304;
// FT: [103][51] gated-value buffer for pool scan; aliases SMEM[0..5252]
// (XB + AGG rows 0..31), all dead after mm2.

// row s, feature i -> dword s*32 + (((i>>2)+s)&7)*4 + (i&3)
__device__ __forceinline__ void row_add4(const float* XB, int s, int cq,
                                         float4&a0, float4&a1, float4&a2, float4&a3){
  int b=s<<5, r=s&7;
  float4 v0=*(const float4*)&XB[b+(((cq  +r)&7)<<2)];
  float4 v1=*(const float4*)&XB[b+(((cq+1+r)&7)<<2)];
  float4 v2=*(const float4*)&XB[b+(((cq+2+r)&7)<<2)];
  float4 v3=*(const float4*)&XB[b+(((cq+3+r)&7)<<2)];
  a0.x+=v0.x; a0.y+=v0.y; a0.z+=v0.z; a0.w+=v0.w;
  a1.x+=v1.x; a1.y+=v1.y; a1.z+=v1.z; a1.w+=v1.w;
  a2.x+=v2.x; a2.y+=v2.y; a2.z+=v2.z; a2.w+=v2.w;
  a3.x+=v3.x; a3.y+=v3.y; a3.z+=v3.z; a3.w+=v3.w;
}

__global__ __launch_bounds__(NT,4) void gnn_fused(
    const float* __restrict__ x, const int* __restrict__ ei,
    const float* __restrict__ W1, const float* __restrict__ b1, const float* __restrict__ p1,
    const float* __restrict__ W2, const float* __restrict__ b2, const float* __restrict__ p2,
    const float* __restrict__ fc1W, const float* __restrict__ fc1b,
    const float* __restrict__ fc2W, const float* __restrict__ fc2b,
    float* __restrict__ out)
{
  const int g=blockIdx.x, tid=threadIdx.x, lane=tid&63, wv=tid>>6;
  const int hf=wv&1;                         // wave-uniform feature half
  const int nG=(tid>>7)*64+lane;             // node: waves{0,1}->0..63, {2,3}->64..127
  const int hfu=__builtin_amdgcn_readfirstlane(hf);
  const int cq=hfu<<2;                       // first of this half's 4 chunks

  __shared__ __align__(16) float SMEM[XBSZ+AGSZ];
  float* XB  = SMEM;
  float* AGG = SMEM+XBSZ;
  float* FT  = SMEM;                          // pool buffer, aliases dead XB/AGG-front
  __shared__ unsigned char eord[EGP];
  __shared__ int cur[NN];
  __shared__ short cstart[NN];
  __shared__ float dsc[NN];                  // dinv1->score1->dinv2->score2
  __shared__ signed char rmap[NN];
  __shared__ int sh_wtot;

  // ---- packed edges + x preloaded into registers ----
  int epk[EPT];
  {
    const int* srcg=ei+(size_t)g*EG;
    const int* dstg=ei+(size_t)BGR*EG+(size_t)g*EG;
    #pragma unroll
    for(int j=0;j<EPT;j++){ int e=tid+j*NT; epk[j]=(srcg[e]&127)|((dstg[e]&127)<<8); }
  }
  float2 xr[8];
  #pragma unroll
  for(int k=0;k<8;k++){
    int l2=tid+k*NT;
    if(l2<NN*15){
      int n=l2/15, i=(l2-n*15)*2;
      xr[k]=*(const float2*)&x[(size_t)g*NN*FIN+n*FIN+i];
    }
  }
  // ---- init: pads, zero row 128, counters ----
  if(tid<NN){ int o=(tid<<5)+(((7+tid)&7)<<2); XB[o+2]=0.f; XB[o+3]=0.f; cur[tid]=0; }
  if(tid>=NN && tid<NN+32) XB[NN*32+(tid-NN)]=0.f;
  __syncthreads();

  // ================= CSR build 1 (pad4, sentinel row 128) =================
  #pragma unroll
  for(int j=0;j<EPT;j++) atomicAdd(&cur[epk[j]>>8],1);
  __syncthreads();
  {
    int mydeg=(tid<NN)?cur[tid]:0;
    int mydeg4=(mydeg+3)&~3;
    int v=mydeg4;
    #pragma unroll
    for(int off=1;off<64;off<<=1){ int t=__shfl_up(v,off,64); if(lane>=off)v+=t; }
    if(tid==63) sh_wtot=v;
    for(int l=tid;l<EGP/4;l+=NT) ((int*)eord)[l]=0x80808080;   // holes -> zero row
    __syncthreads();
    if(tid<NN){
      int start=v-mydeg4+((tid>=64)?sh_wtot:0);
      cur[tid]=start; cstart[tid]=(short)start;
      dsc[tid]=1.0f/sqrtf((float)mydeg+1.0f);                  // dinv1
    }
  }
  __syncthreads();
  // ---- stage x scaled by dinv1 (from regs) + scatter1 (one phase) ----
  #pragma unroll
  for(int k=0;k<8;k++){
    int l2=tid+k*NT;
    if(l2<NN*15){
      int n=l2/15, i=(l2-n*15)*2;
      float di=dsc[n];
      float2 v=xr[k]; v.x*=di; v.y*=di;
      *(float2*)&XB[(n<<5)+((((i>>2)+n)&7)<<2)+(i&3)]=v;
    }
  }
  #pragma unroll
  for(int j=0;j<EPT;j++){ int p=atomicAdd(&cur[epk[j]>>8],1); eord[p]=(unsigned char)(epk[j]&255); }
  __syncthreads();

  // ================= gather1: pure row-sum, final x dinv1 ====================
  {
    float4 a0={0,0,0,0},a1={0,0,0,0},a2={0,0,0,0},a3={0,0,0,0};
    int e0=cstart[nG], deg=cur[nG]-e0;
    int kend=e0+((deg+3)&~3);
    for(int k=e0;k<kend;k+=4){
      uchar4 ss=*(const uchar4*)&eord[k];
      row_add4(XB,ss.x,cq,a0,a1,a2,a3);
      row_add4(XB,ss.y,cq,a0,a1,a2,a3);
      row_add4(XB,ss.z,cq,a0,a1,a2,a3);
      row_add4(XB,ss.w,cq,a0,a1,a2,a3);
    }
    row_add4(XB,nG,cq,a0,a1,a2,a3);          // self: dinv*(... + x'[n])
    float di=dsc[nG];
    a0.x*=di; a0.y*=di; a0.z*=di; a0.w*=di;
    a1.x*=di; a1.y*=di; a1.z*=di; a1.w*=di;
    a2.x*=di; a2.y*=di; a2.z*=di; a2.w*=di;
    a3.x*=di; a3.y*=di; a3.z*=di; a3.w*=di;
    float* dp=&AGG[nG*SA + (hfu<<4)];        // half0 -> feats 0..15, half1 -> 16..29
    ((float4*)dp)[0]=a0; ((float4*)dp)[1]=a1; ((float4*)dp)[2]=a2;
    if(!hfu) ((float4*)dp)[3]=a3;
    else     *(float2*)(dp+12)=make_float2(a3.x,a3.y);
  }
  __syncthreads();                 // x' dead; agg1 ready

  // ================= mm1: scalar-W (wave-uniform) ============================
  float h[15];
  {
    float A[30];
    {
      const float* arow=&AGG[nG*SA];
      float4 t0=((const float4*)arow)[0],t1=((const float4*)arow)[1],t2=((const float4*)arow)[2],
             t3=((const float4*)arow)[3],t4=((const float4*)arow)[4],t5=((const float4*)arow)[5],
             t6=((const float4*)arow)[6];
      float2 t7=*(const float2*)(arow+28);
      A[0]=t0.x;A[1]=t0.y;A[2]=t0.z;A[3]=t0.w; A[4]=t1.x;A[5]=t1.y;A[6]=t1.z;A[7]=t1.w;
      A[8]=t2.x;A[9]=t2.y;A[10]=t2.z;A[11]=t2.w; A[12]=t3.x;A[13]=t3.y;A[14]=t3.z;A[15]=t3.w;
      A[16]=t4.x;A[17]=t4.y;A[18]=t4.z;A[19]=t4.w; A[20]=t5.x;A[21]=t5.y;A[22]=t5.z;A[23]=t5.w;
      A[24]=t6.x;A[25]=t6.y;A[26]=t6.z;A[27]=t6.w; A[28]=t7.x;A[29]=t7.y;
    }
    const float* W1u=W1+hfu*15;
    const float* b1u=b1+hfu*15;
    #pragma unroll
    for(int jo=0;jo<15;jo++) h[jo]=b1u[jo];
    #pragma unroll
    for(int i=0;i<FIN;i++){
      float ai=A[i];
      #pragma unroll
      for(int jo=0;jo<15;jo++) h[jo]=fmaf(ai,W1u[i*H1+jo],h[jo]);
    }
    #pragma unroll
    for(int jo=0;jo<15;jo++) h[jo]=fmaxf(h[jo],0.f);
  }

  // ---- pool1 partial score (per half) ----
  {
    const float* p1u=p1+hfu*15;
    float d=0.f;
    #pragma unroll
    for(int jo=0;jo<15;jo++) d += h[jo]*p1u[jo];
    AGG[SD0 + hf*128 + nG]=d;
  }
  __syncthreads();
  if(tid<NN){
    float nr=0.f;
    #pragma unroll
    for(int i=0;i<H1;i++){ float pv=p1[i]; nr+=pv*pv; }
    float dt=AGG[SD0+tid]+AGG[SD0+128+tid];
    dsc[tid]=tanhf(dt/sqrtf(nr));            // score1
  }
  __syncthreads();
  {  // stable rank (pair-split) == jax.lax.top_k order
    int nR=tid>>1, hR=tid&1;
    float si=dsc[nR];
    int m0=hR<<6, r=0;
    for(int m=m0;m<m0+64;m++){ float sm=dsc[m]; r += (sm>si)||(sm==si&&m<nR); }
    r += __shfl_xor(r,1,64);
    if(!hR) rmap[nR]=(r<K1)?(signed char)r:(signed char)-1;
  }
  __syncthreads();
  {  // gated compact -> swizzled XB rank rows (score only; dinv2 by prescale2)
    int r=rmap[nG];
    if(r>=0){
      float gv=dsc[nG];
      #pragma unroll
      for(int j=0;j<15;j++){
        int i=hfu*15+j;
        XB[(r<<5)+((((i>>2)+r)&7)<<2)+(i&3)]=h[j]*gv;
      }
    }
  }
  #pragma unroll
  for(int j=0;j<EPT;j++){
    int ns=rmap[epk[j]&255], nd=rmap[epk[j]>>8];
    epk[j]=((ns|nd)<0)? -1 : (ns|(nd<<8));
  }
  if(tid<K1) cur[tid]=0;
  __syncthreads();

  // ================= CSR build 2 (pruned, rank ids) =================
  #pragma unroll
  for(int j=0;j<EPT;j++) if(epk[j]>=0) atomicAdd(&cur[epk[j]>>8],1);
  __syncthreads();
  {
    int mydeg=(tid<K1)?cur[tid]:0;
    int mydeg4=(mydeg+3)&~3;
    int v=mydeg4;
    #pragma unroll
    for(int off=1;off<64;off<<=1){ int t=__shfl_up(v,off,64); if(lane>=off)v+=t; }
    if(tid==63) sh_wtot=v;
    for(int l=tid;l<EGP/4;l+=NT) ((int*)eord)[l]=0x80808080;
    __syncthreads();
    if(tid<K1){
      int start=v-mydeg4+((tid>=64)?sh_wtot:0);
      cur[tid]=start; cstart[tid]=(short)start;
      dsc[tid]=1.0f/sqrtf((float)mydeg+1.0f);            // dinv2 (by rank id)
    }
  }
  __syncthreads();
  // ---- scatter2 + prescale2 fused (disjoint targets: eord vs XB rank rows) ----
  #pragma unroll
  for(int j=0;j<EPT;j++) if(epk[j]>=0){ int p=atomicAdd(&cur[epk[j]>>8],1); eord[p]=(unsigned char)(epk[j]&255); }
  if(nG<K1){
    float d2=dsc[nG];
    int b=nG<<5, r=nG&7;
    #pragma unroll
    for(int c=0;c<4;c++){
      float4* q=(float4*)&XB[b+((((cq+c)+r)&7)<<2)];
      float4 v=*q;
      v.x*=d2; v.y*=d2; v.z*=d2; v.w*=d2;
      *q=v;
    }
  }
  __syncthreads();

  // ================= gather2: pure row-sum (pruned CSR), final x dinv2 =======
  if(nG<K1){
    float4 a0={0,0,0,0},a1={0,0,0,0},a2={0,0,0,0},a3={0,0,0,0};
    int e0=cstart[nG], deg=cur[nG]-e0;
    int kend=e0+((deg+3)&~3);
    for(int k=e0;k<kend;k+=4){
      uchar4 ss=*(const uchar4*)&eord[k];
      row_add4(XB,ss.x,cq,a0,a1,a2,a3);
      row_add4(XB,ss.y,cq,a0,a1,a2,a3);
      row_add4(XB,ss.z,cq,a0,a1,a2,a3);
      row_add4(XB,ss.w,cq,a0,a1,a2,a3);
    }
    row_add4(XB,nG,cq,a0,a1,a2,a3);
    float d2=dsc[nG];
    a0.x*=d2; a0.y*=d2; a0.z*=d2; a0.w*=d2;
    a1.x*=d2; a1.y*=d2; a1.z*=d2; a1.w*=d2;
    a2.x*=d2; a2.y*=d2; a2.z*=d2; a2.w*=d2;
    a3.x*=d2; a3.y*=d2; a3.z*=d2; a3.w*=d2;
    float* dp=&AGG[nG*SA + (hfu<<4)];
    ((float4*)dp)[0]=a0; ((float4*)dp)[1]=a1; ((float4*)dp)[2]=a2;
    if(!hfu) ((float4*)dp)[3]=a3;
    else     *(float2*)(dp+12)=make_float2(a3.x,a3.y);
  }
  __syncthreads();                 // agg2 ready

  // ================= mm2: scalar-W + pool2 partial ===========================
  float oc[25];
  if(nG<K1){
    float A[30];
    {
      const float* arow=&AGG[nG*SA];
      float4 t0=((const float4*)arow)[0],t1=((const float4*)arow)[1],t2=((const float4*)arow)[2],
             t3=((const float4*)arow)[3],t4=((const float4*)arow)[4],t5=((const float4*)arow)[5],
             t6=((const float4*)arow)[6];
      float2 t7=*(const float2*)(arow+28);
      A[0]=t0.x;A[1]=t0.y;A[2]=t0.z;A[3]=t0.w; A[4]=t1.x;A[5]=t1.y;A[6]=t1.z;A[7]=t1.w;
      A[8]=t2.x;A[9]=t2.y;A[10]=t2.z;A[11]=t2.w; A[12]=t3.x;A[13]=t3.y;A[14]=t3.z;A[15]=t3.w;
      A[16]=t4.x;A[17]=t4.y;A[18]=t4.z;A[19]=t4.w; A[20]=t5.x;A[21]=t5.y;A[22]=t5.z;A[23]=t5.w;
      A[24]=t6.x;A[25]=t6.y;A[26]=t6.z;A[27]=t6.w; A[28]=t7.x;A[29]=t7.y;
    }
    const float* W2u=W2+hfu*25;
    const float* b2u=b2+hfu*25;
    #pragma unroll
    for(int jo=0;jo<25;jo++) oc[jo]=b2u[jo];
    #pragma unroll
    for(int i=0;i<H1;i++){
      float ai=A[i];
      #pragma unroll
      for(int jo=0;jo<25;jo++) oc[jo]=fmaf(ai,W2u[i*H2+jo],oc[jo]);
    }
    const float* p2u=p2+hfu*25;
    float d=0.f;
    #pragma unroll
    for(int jo=0;jo<25;jo++){ oc[jo]=fmaxf(oc[jo],0.f); d += oc[jo]*p2u[jo]; }
    AGG[SD0 + hf*128 + nG]=d;
  }
  __syncthreads();
  if(tid<K1){
    float nr=0.f;
    #pragma unroll
    for(int i=0;i<H2;i++){ float pv=p2[i]; nr+=pv*pv; }
    float dt=AGG[SD0+tid]+AGG[SD0+128+tid];
    dsc[tid]=tanhf(dt/sqrtf(nr));            // score2
  }
  __syncthreads();
  {  // rank2 (pair-split, keep flag)
    int nR=tid>>1, hR=tid&1;
    float si=(nR<K1)?dsc[nR]:0.f;
    int m0=hR?52:0, m1=hR?K1:52, r=0;
    for(int m=m0;m<m1;m++){ float sm=dsc[m]; r += (sm>si)||(sm==si&&m<nR); }
    r += __shfl_xor(r,1,64);
    if(!hR && nR<K1) rmap[nR]=(r<K2)?(signed char)1:(signed char)-1;
  }
  __syncthreads();

  // ================= gated pool via FT column scan (XB/AGG-front dead) =======
  if(nG<K1){
    bool kept=rmap[nG]>0;
    float gv=kept?dsc[nG]:0.f;
    #pragma unroll
    for(int j=0;j<25;j++){
      FT[nG*51 + hfu*25 + j] = kept ? oc[j]*gv : -3.4e38f;
    }
  }
  __syncthreads();
  if(tid<H2){
    float mx=-3.4e38f, sm=0.f;
    for(int n=0;n<K1;n++){
      float v=FT[n*51+tid];
      mx=fmaxf(mx,v);
      sm += (v>-1.0e30f)? v : 0.f;
    }
    AGG[POL+tid]=mx;
    AGG[POL+H2+tid]=sm*(1.0f/(float)K2);
  }
  __syncthreads();

  // ================= fc1 (float4 pol reads) + fc2 =================
  if(tid<FCW){
    float acc=fc1b[tid];
    #pragma unroll
    for(int i4=0;i4<25;i4++){
      float4 pv=*(const float4*)&AGG[POL+i4*4];
      int i=i4*4;
      acc=fmaf(pv.x,fc1W[(i  )*FCW+tid],acc);
      acc=fmaf(pv.y,fc1W[(i+1)*FCW+tid],acc);
      acc=fmaf(pv.z,fc1W[(i+2)*FCW+tid],acc);
      acc=fmaf(pv.w,fc1W[(i+3)*FCW+tid],acc);
    }
    AGG[ZFC+tid]=fmaxf(acc,0.f);
  }
  __syncthreads();
  if(tid<64){
    float a=0.f;
    for(int j=tid;j<FCW;j+=64) a += AGG[ZFC+j]*fc2W[j];
    #pragma unroll
    for(int off=32;off;off>>=1) a += __shfl_down(a,off,64);
    if(tid==0) out[g]=1.0f/(1.0f+expf(-(fc2b[0]+a)));
  }
}

extern "C" void kernel_launch(void* const* d_in, const int* in_sizes, int n_in,
                              void* d_out, int out_size, void* d_ws, size_t ws_size,
                              hipStream_t stream) {
  const float* x    = (const float*)d_in[0];
  const int*   ei   = (const int*)d_in[1];
  // d_in[2] = batch (unused; graphs are equal-size, contiguous)
  const float* W1   = (const float*)d_in[3];
  const float* b1   = (const float*)d_in[4];
  const float* p1   = (const float*)d_in[5];
  const float* W2   = (const float*)d_in[6];
  const float* b2   = (const float*)d_in[7];
  const float* p2   = (const float*)d_in[8];
  const float* fc1W = (const float*)d_in[9];
  const float* fc1b = (const float*)d_in[10];
  const float* fc2W = (const float*)d_in[11];
  const float* fc2b = (const float*)d_in[12];
  float* outp = (float*)d_out;

  gnn_fused<<<BGR, NT, 0, stream>>>(x, ei, W1, b1, p1, W2, b2, p2,
                                    fc1W, fc1b, fc2W, fc2b, outp);
}